// Round 8
// baseline (313.363 us; speedup 1.0000x reference)
//
#include <hip/hip_runtime.h>

// HashRouter via MFMA: h = x @ W^T + b computed as bf16 hi/lo split GEMM
// (fp32 ~= hi + lo; products hh+hl+lh; dropped ll + lo-rounding + fp32-accum
// error ~1e-5 << TH=5e-5, borderliners re-checked exact in fp64).
// R3-R9 established the VALU+LDS structure is pinned at VALUBusy ~22% /
// 160 us regardless of occupancy (R5/R8) or pipeline depth (R9) --
// ds_read->FMA chains + lockstep are structural. R10/R11 removes the
// structure: NO LDS, NO barriers in the K-loop; fragments load DIRECTLY
// from global (x streams from HBM once; W fp32 is L2-resident, 512 KB,
// shared by all blocks). R11 vs R10: d_ws dependency REMOVED (R10's
// wsplit wrote 512 KB to d_ws with unknown ws_size -- possible OOB ->
// container fault). B is split hi/lo in-register from fp32 w, same bytes
// (hi+lo bf16 = 4 B/elem = fp32), ~8.5 us extra VALU GPU-wide, under the
// ~21 us HBM floor. Also fixed: lane>=16 shift-UB in the ballot epilogue.
// k-slot order inside a frag is self-cancelling (A and B use the same
// (lane>>4,e)->k map); load-bearing layout facts: operand row = lane&15,
// C/D = D[tok=(lane>>4)*4+reg][j=16*jt+(lane&15)] (m89-verified).
// Decomposition: wave = 16 tok x 64 j x K/4; block = 4 waves (k-quarters),
// one 12 KB LDS reduce + single __syncthreads at the end; grid 1024.

constexpr int H_DIM  = 2048;
constexpr int NJ     = 64;
constexpr int TOKB   = 16;      // tokens per block
constexpr int KW     = 512;     // K-span per wave
constexpr int KSTEPS = KW / 32; // 16 MFMA K-steps per wave

typedef __attribute__((ext_vector_type(8))) short  bf16x8;
typedef __attribute__((ext_vector_type(4))) float  f32x4;

__device__ __forceinline__ unsigned int bf16rne(float f) {
    unsigned int u = __float_as_uint(f);
    return (u + 0x7FFFu + ((u >> 16) & 1u)) >> 16;   // RNE, finite inputs
}

// fp32[8] -> bf16 hi (truncated top16, exact residual) + bf16 lo (RNE).
__device__ __forceinline__ void split8(const f32x4 a0, const f32x4 a1,
                                       bf16x8& hi, bf16x8& lo) {
    union { bf16x8 v; unsigned int u[4]; } H, L;
    const unsigned int u0 = __float_as_uint(a0.x), u1 = __float_as_uint(a0.y);
    const unsigned int u2 = __float_as_uint(a0.z), u3 = __float_as_uint(a0.w);
    const unsigned int u4 = __float_as_uint(a1.x), u5 = __float_as_uint(a1.y);
    const unsigned int u6 = __float_as_uint(a1.z), u7 = __float_as_uint(a1.w);
    H.u[0] = (u0 >> 16) | (u1 & 0xFFFF0000u);
    H.u[1] = (u2 >> 16) | (u3 & 0xFFFF0000u);
    H.u[2] = (u4 >> 16) | (u5 & 0xFFFF0000u);
    H.u[3] = (u6 >> 16) | (u7 & 0xFFFF0000u);
    const float l0 = a0.x - __uint_as_float(u0 & 0xFFFF0000u);
    const float l1 = a0.y - __uint_as_float(u1 & 0xFFFF0000u);
    const float l2 = a0.z - __uint_as_float(u2 & 0xFFFF0000u);
    const float l3 = a0.w - __uint_as_float(u3 & 0xFFFF0000u);
    const float l4 = a1.x - __uint_as_float(u4 & 0xFFFF0000u);
    const float l5 = a1.y - __uint_as_float(u5 & 0xFFFF0000u);
    const float l6 = a1.z - __uint_as_float(u6 & 0xFFFF0000u);
    const float l7 = a1.w - __uint_as_float(u7 & 0xFFFF0000u);
    L.u[0] = bf16rne(l0) | (bf16rne(l1) << 16);
    L.u[1] = bf16rne(l2) | (bf16rne(l3) << 16);
    L.u[2] = bf16rne(l4) | (bf16rne(l5) << 16);
    L.u[3] = bf16rne(l6) | (bf16rne(l7) << 16);
    hi = H.v; lo = L.v;
}

__global__ __launch_bounds__(256, 2) void hash_mfma_kernel(
    const float* __restrict__ x,             // [T, H] fp32
    const float* __restrict__ w,             // [64, H] fp32
    const float* __restrict__ b,             // [64]
    float* __restrict__ out,                 // [2T | 2T | 64T]
    int T)
{
    __shared__ float red[3 * 64 * 16];       // 12 KB cross-wave reduce

    const int tid  = threadIdx.x;
    const int wv   = tid >> 6;               // wave = k-quarter (0..3)
    const int lane = tid & 63;
    const int row  = lane & 15;              // A row (token) / B row (j%16)
    const int kq   = lane >> 4;              // k-octet group within K=32
    const int tokB = blockIdx.x * TOKB;

    // Per-lane fragment base pointers (k = wv*512 + ks*32 + kq*8 + e).
    const float* xA = x + (size_t)(tokB + row) * H_DIM + wv * KW + kq * 8;
    const float* wB = w + (size_t)row * H_DIM + wv * KW + kq * 8;

    f32x4 acc[4];
#pragma unroll
    for (int jt = 0; jt < 4; ++jt) acc[jt] = (f32x4){0.f, 0.f, 0.f, 0.f};

    // ---- K-loop: pure streaming, no LDS, no barriers.
#pragma unroll 2
    for (int ks = 0; ks < KSTEPS; ++ks) {
        const int k0 = ks * 32;
        bf16x8 AH, AL;
        {
            const f32x4 a0 = *(const f32x4*)(xA + k0);
            const f32x4 a1 = *(const f32x4*)(xA + k0 + 4);
            split8(a0, a1, AH, AL);
        }
#pragma unroll
        for (int jt = 0; jt < 4; ++jt) {
            const float* wp = wB + (size_t)jt * 16 * H_DIM + k0;
            const f32x4 b0 = *(const f32x4*)(wp);
            const f32x4 b1 = *(const f32x4*)(wp + 4);
            bf16x8 BH, BL;
            split8(b0, b1, BH, BL);
            acc[jt] = __builtin_amdgcn_mfma_f32_16x16x32_bf16(AL, BH, acc[jt], 0, 0, 0);
            acc[jt] = __builtin_amdgcn_mfma_f32_16x16x32_bf16(AH, BL, acc[jt], 0, 0, 0);
            acc[jt] = __builtin_amdgcn_mfma_f32_16x16x32_bf16(AH, BH, acc[jt], 0, 0, 0);
        }
    }

    // ---- Cross-wave k-quarter reduce (the only barrier).
    if (wv) {
        float* rp = red + ((wv - 1) * 64 + lane) * 16;
#pragma unroll
        for (int jt = 0; jt < 4; ++jt) *(f32x4*)(rp + jt * 4) = acc[jt];
    }
    __syncthreads();

    if (wv == 0) {
#pragma unroll
        for (int w2 = 0; w2 < 3; ++w2)
#pragma unroll
            for (int jt = 0; jt < 4; ++jt) {
                const f32x4 t = *(const f32x4*)(red + (w2 * 64 + lane) * 16 + jt * 4);
                acc[jt].x += t.x; acc[jt].y += t.y; acc[jt].z += t.z; acc[jt].w += t.w;
            }

        float bias[4];
#pragma unroll
        for (int jt = 0; jt < 4; ++jt) bias[jt] = b[jt * 16 + row];

        // C/D layout (m89): lane holds D[tok=(lane>>4)*4+r][j=jt*16+(lane&15)].
        // Sign -> ballot -> per-token popcount. Lane t<16 owns token t:
        // its 16 j-lanes live at ballot bits [(t>>2)*16, +16), valid when
        // r == (t&3).
        const float TH = 5e-5f;
        int c0 = 0, c1 = 0;
        const int myg = (lane >> 2) & 3;     // &3: avoid shift-UB for lane>=16
        const int myr = lane & 3;
#pragma unroll
        for (int jt = 0; jt < 4; ++jt)
#pragma unroll
            for (int r = 0; r < 4; ++r) {
                const float h = acc[jt][r] + bias[jt];
                bool pos;
                if (__builtin_expect(fabsf(h) < TH, 0)) {
                    // split error ~1e-5 < TH: exact fp64 recheck (rare).
                    const float* xr = x + (size_t)(tokB + (lane >> 4) * 4 + r) * H_DIM;
                    const float* wr = w + (size_t)(jt * 16 + row) * H_DIM;
                    double sd = (double)bias[jt];
                    for (int k = 0; k < H_DIM; ++k)
                        sd += (double)xr[k] * (double)wr[k];
                    pos = (sd > 0.0);
                } else {
                    pos = (h > 0.0f);
                }
                const unsigned long long bal = __ballot(pos);
                const int add = ((myr == r) ? 1 : 0) *
                    __popc((unsigned int)((bal >> (myg * 16)) & 0xFFFFu));
                if (jt < 2) c0 += add; else c1 += add;
            }

        if (lane < TOKB) {
            const int t  = tokB + lane;
            const int i1 = c1 + ((c1 == c0) ? 1 : 0);
            float2 wq; wq.x = 0.5f; wq.y = 0.5f;
            *(float2*)(out + 2 * (size_t)t) = wq;
            float2 iq; iq.x = (float)c0; iq.y = (float)i1;
            *(float2*)(out + 2 * (size_t)T + 2 * (size_t)t) = iq;
        }
    }

    // router_logits = 0: 16 tok x 64 = 1024 floats = 256 f32x4, one/thread.
    f32x4 z = (f32x4){0.f, 0.f, 0.f, 0.f};
    *(f32x4*)(out + 4 * (size_t)T + (size_t)tokB * NJ + (size_t)tid * 4) = z;
}

extern "C" void kernel_launch(void* const* d_in, const int* in_sizes, int n_in,
                              void* d_out, int out_size, void* d_ws, size_t ws_size,
                              hipStream_t stream) {
    const float* x = (const float*)d_in[0];
    const float* w = (const float*)d_in[1];
    const float* b = (const float*)d_in[2];
    float* out = (float*)d_out;
    const int T = in_sizes[0] / H_DIM;               // 16384
    hash_mfma_kernel<<<dim3(T / TOKB), dim3(256), 0, stream>>>(x, w, b, out, T);
}

// Round 10
// 284.465 us; speedup vs baseline: 1.1016x; 1.1016x over previous
//
#include <hip/hip_runtime.h>

// HashRouter via MFMA bf16 hi/lo split GEMM (fp32 ~= hi+lo; hh+hl+lh;
// error ~1e-5 << TH=5e-5, borderliners re-checked exact in fp64).
// R13 == R12 resubmitted: container-level infra failure (3rd this session,
// ~every other round); source audited bounds-clean (LOADA/LOADB max offset
// 2047 < H_DIM for all rows; clamped tail duplicates are valid addresses;
// epilogue byte-identical to R11 which ran and passed; no d_ws).
// R11 result: correct (absmax 0) but 183 us with VALUBusy 15% / MfmaUtil
// 2.6% -- pure load-latency bound: each K-step's 10 global loads (A: HBM
// ~900cy, B: L2 ~200-300cy) feed splits/MFMAs in the SAME step, prefetch
// distance ~0. R12: explicit register software-pipeline (T14 in regs, all
// buffers NAMED -- rule #20). A double-buffered by step-parity (arE/arO),
// prefetch distance 2 K-steps (~1000cy cover). B per-jt buffers br0..br3,
// distance 4 micro-steps (~500cy cover). Loads issued immediately after
// their buffer is split (WAR dep pins the order); consumers never wait.
// Floor arithmetic: split VALU ~13us GPU-wide + x stream 21us + W/L2 15us
// + MFMA 6.4us -> ~35-50us achievable vs 183 measured in R11.
// Layout facts (load-bearing, verified by R11 absmax=0): operand row =
// lane&15, k-slot order self-cancelling (A,B share (lane>>4,e)->k map),
// C/D = D[tok=(lane>>4)*4+reg][j=16*jt+(lane&15)] (m89).

constexpr int H_DIM  = 2048;
constexpr int NJ     = 64;
constexpr int TOKB   = 16;      // tokens per block
constexpr int KW     = 512;     // K-span per wave
constexpr int KSTEPS = KW / 32; // 16 MFMA K-steps per wave

typedef __attribute__((ext_vector_type(8))) short  bf16x8;
typedef __attribute__((ext_vector_type(4))) float  f32x4;

struct raw8 { f32x4 lo, hi; };  // 8 fp32 = one MFMA operand fragment, pre-split

__device__ __forceinline__ unsigned int bf16rne(float f) {
    unsigned int u = __float_as_uint(f);
    return (u + 0x7FFFu + ((u >> 16) & 1u)) >> 16;   // RNE, finite inputs
}

// fp32[8] -> bf16 hi (truncated top16, exact residual) + bf16 lo (RNE).
__device__ __forceinline__ void split8(const f32x4 a0, const f32x4 a1,
                                       bf16x8& hi, bf16x8& lo) {
    union { bf16x8 v; unsigned int u[4]; } H, L;
    const unsigned int u0 = __float_as_uint(a0.x), u1 = __float_as_uint(a0.y);
    const unsigned int u2 = __float_as_uint(a0.z), u3 = __float_as_uint(a0.w);
    const unsigned int u4 = __float_as_uint(a1.x), u5 = __float_as_uint(a1.y);
    const unsigned int u6 = __float_as_uint(a1.z), u7 = __float_as_uint(a1.w);
    H.u[0] = (u0 >> 16) | (u1 & 0xFFFF0000u);
    H.u[1] = (u2 >> 16) | (u3 & 0xFFFF0000u);
    H.u[2] = (u4 >> 16) | (u5 & 0xFFFF0000u);
    H.u[3] = (u6 >> 16) | (u7 & 0xFFFF0000u);
    const float l0 = a0.x - __uint_as_float(u0 & 0xFFFF0000u);
    const float l1 = a0.y - __uint_as_float(u1 & 0xFFFF0000u);
    const float l2 = a0.z - __uint_as_float(u2 & 0xFFFF0000u);
    const float l3 = a0.w - __uint_as_float(u3 & 0xFFFF0000u);
    const float l4 = a1.x - __uint_as_float(u4 & 0xFFFF0000u);
    const float l5 = a1.y - __uint_as_float(u5 & 0xFFFF0000u);
    const float l6 = a1.z - __uint_as_float(u6 & 0xFFFF0000u);
    const float l7 = a1.w - __uint_as_float(u7 & 0xFFFF0000u);
    L.u[0] = bf16rne(l0) | (bf16rne(l1) << 16);
    L.u[1] = bf16rne(l2) | (bf16rne(l3) << 16);
    L.u[2] = bf16rne(l4) | (bf16rne(l5) << 16);
    L.u[3] = bf16rne(l6) | (bf16rne(l7) << 16);
    hi = H.v; lo = L.v;
}

__global__ __launch_bounds__(256, 2) void hash_mfma_kernel(
    const float* __restrict__ x,             // [T, H] fp32
    const float* __restrict__ w,             // [64, H] fp32
    const float* __restrict__ b,             // [64]
    float* __restrict__ out,                 // [2T | 2T | 64T]
    int T)
{
    __shared__ float red[3 * 64 * 16];       // 12 KB cross-wave reduce

    const int tid  = threadIdx.x;
    const int wv   = tid >> 6;               // wave = k-quarter (0..3)
    const int lane = tid & 63;
    const int row  = lane & 15;              // A row (token) / B row (j%16)
    const int kq   = lane >> 4;              // k-octet group within K=32
    const int tokB = blockIdx.x * TOKB;

    // Per-lane fragment bases (k = wv*512 + ks*32 + kq*8 + e).
    const float* xA = x + (size_t)(tokB + row) * H_DIM + wv * KW + kq * 8;
    const float* wB = w + (size_t)row * H_DIM + wv * KW + kq * 8;

#define LOADA(dst, kk) { dst.lo = *(const f32x4*)(xA + (kk) * 32); \
                         dst.hi = *(const f32x4*)(xA + (kk) * 32 + 4); }
#define LOADB(dst, kk, jt) { const float* wp_ = wB + (size_t)(jt) * 16 * H_DIM + (kk) * 32; \
                             dst.lo = *(const f32x4*)(wp_); \
                             dst.hi = *(const f32x4*)(wp_ + 4); }

    f32x4 acc[4];
#pragma unroll
    for (int jt = 0; jt < 4; ++jt) acc[jt] = (f32x4){0.f, 0.f, 0.f, 0.f};

    // ---- Pipelined K-loop: no LDS, no barriers, loads 1-2 steps ahead.
    raw8 arE, arO, br0, br1, br2, br3;
    LOADA(arE, 0); LOADA(arO, 1);            // A: steps 0,1 in flight
    LOADB(br0, 0, 0); LOADB(br1, 0, 1);      // B: step 0, all jt in flight
    LOADB(br2, 0, 2); LOADB(br3, 0, 3);

    // JT: split B (frees brv), immediately re-issue brv <- (kNext, jt),
    // then 3 MFMAs. WAR on brv pins split-before-load; load lands while
    // later micro-steps compute (distance 4 micro-steps ~500cy >= L2 lat).
#define JT_STEP(jt, brv, kNext) { \
        bf16x8 BH, BL; split8(brv.lo, brv.hi, BH, BL); \
        LOADB(brv, kNext, jt); \
        acc[jt] = __builtin_amdgcn_mfma_f32_16x16x32_bf16(AL, BH, acc[jt], 0, 0, 0); \
        acc[jt] = __builtin_amdgcn_mfma_f32_16x16x32_bf16(AH, BL, acc[jt], 0, 0, 0); \
        acc[jt] = __builtin_amdgcn_mfma_f32_16x16x32_bf16(AH, BH, acc[jt], 0, 0, 0); }

#pragma unroll 1
    for (int ks = 0; ks < KSTEPS; ks += 2) {
        // -- even step ks: consume arE, br*(ks); refill arE <- ks+2.
        {
            bf16x8 AH, AL;
            split8(arE.lo, arE.hi, AH, AL);
            const int kA = (ks + 2 < KSTEPS) ? ks + 2 : KSTEPS - 1;  // clamped dup: harmless
            LOADA(arE, kA);
            JT_STEP(0, br0, ks + 1); JT_STEP(1, br1, ks + 1);
            JT_STEP(2, br2, ks + 1); JT_STEP(3, br3, ks + 1);
        }
        // -- odd step ks+1: consume arO, br*(ks+1); refill arO <- ks+3.
        {
            bf16x8 AH, AL;
            split8(arO.lo, arO.hi, AH, AL);
            const int kA = (ks + 3 < KSTEPS) ? ks + 3 : KSTEPS - 1;
            LOADA(arO, kA);
            const int kB = (ks + 2 < KSTEPS) ? ks + 2 : KSTEPS - 1;
            JT_STEP(0, br0, kB); JT_STEP(1, br1, kB);
            JT_STEP(2, br2, kB); JT_STEP(3, br3, kB);
        }
    }

    // ---- Cross-wave k-quarter reduce (the only barrier).
    if (wv) {
        float* rp = red + ((wv - 1) * 64 + lane) * 16;
#pragma unroll
        for (int jt = 0; jt < 4; ++jt) *(f32x4*)(rp + jt * 4) = acc[jt];
    }
    __syncthreads();

    if (wv == 0) {
#pragma unroll
        for (int w2 = 0; w2 < 3; ++w2)
#pragma unroll
            for (int jt = 0; jt < 4; ++jt) {
                const f32x4 t = *(const f32x4*)(red + (w2 * 64 + lane) * 16 + jt * 4);
                acc[jt].x += t.x; acc[jt].y += t.y; acc[jt].z += t.z; acc[jt].w += t.w;
            }

        float bias[4];
#pragma unroll
        for (int jt = 0; jt < 4; ++jt) bias[jt] = b[jt * 16 + row];

        // C/D layout (m89): lane holds D[tok=(lane>>4)*4+r][j=jt*16+(lane&15)].
        // Sign -> ballot -> per-token popcount; lane t<16 owns token t.
        const float TH = 5e-5f;
        int c0 = 0, c1 = 0;
        const int myg = (lane >> 2) & 3;     // &3: no shift-UB for lane>=16
        const int myr = lane & 3;
#pragma unroll
        for (int jt = 0; jt < 4; ++jt)
#pragma unroll
            for (int r = 0; r < 4; ++r) {
                const float h = acc[jt][r] + bias[jt];
                bool pos;
                if (__builtin_expect(fabsf(h) < TH, 0)) {
                    // split error ~1e-5 < TH: exact fp64 recheck (rare).
                    const float* xr = x + (size_t)(tokB + (lane >> 4) * 4 + r) * H_DIM;
                    const float* wr = w + (size_t)(jt * 16 + row) * H_DIM;
                    double sd = (double)bias[jt];
                    for (int k = 0; k < H_DIM; ++k)
                        sd += (double)xr[k] * (double)wr[k];
                    pos = (sd > 0.0);
                } else {
                    pos = (h > 0.0f);
                }
                const unsigned long long bal = __ballot(pos);
                const int add = ((myr == r) ? 1 : 0) *
                    __popc((unsigned int)((bal >> (myg * 16)) & 0xFFFFu));
                if (jt < 2) c0 += add; else c1 += add;
            }

        if (lane < TOKB) {
            const int t  = tokB + lane;
            const int i1 = c1 + ((c1 == c0) ? 1 : 0);
            float2 wq; wq.x = 0.5f; wq.y = 0.5f;
            *(float2*)(out + 2 * (size_t)t) = wq;
            float2 iq; iq.x = (float)c0; iq.y = (float)i1;
            *(float2*)(out + 2 * (size_t)T + 2 * (size_t)t) = iq;
        }
    }

    // router_logits = 0: 16 tok x 64 = 1024 floats = 256 f32x4, one/thread.
    f32x4 z = (f32x4){0.f, 0.f, 0.f, 0.f};
    *(f32x4*)(out + 4 * (size_t)T + (size_t)tokB * NJ + (size_t)tid * 4) = z;
}

extern "C" void kernel_launch(void* const* d_in, const int* in_sizes, int n_in,
                              void* d_out, int out_size, void* d_ws, size_t ws_size,
                              hipStream_t stream) {
    const float* x = (const float*)d_in[0];
    const float* w = (const float*)d_in[1];
    const float* b = (const float*)d_in[2];
    float* out = (float*)d_out;
    const int T = in_sizes[0] / H_DIM;               // 16384
    hash_mfma_kernel<<<dim3(T / TOKB), dim3(256), 0, stream>>>(x, w, b, out, T);
}